// Round 4
// baseline (270.621 us; speedup 1.0000x reference)
//
#include <hip/hip_runtime.h>
#include <hip/hip_bf16.h>
#include <stdint.h>

#define D_MODEL 1024
#define N_HEADS 16
#define HEAD_DIM 64
#define B_SZ 4
#define T_SEQ 2048
#define BH_TOT (B_SZ * N_HEADS)     // 64
#define M_ROWS (B_SZ * T_SEQ)       // 8192

typedef float floatx4 __attribute__((ext_vector_type(4)));
typedef __bf16 bf16x8 __attribute__((ext_vector_type(8)));

__device__ inline unsigned short f2bf(float f) {
  union { float f; unsigned int u; } c; c.f = f;
  unsigned int u = c.u;
  unsigned int r = (u + 0x7FFFu + ((u >> 16) & 1u)) >> 16;
  return (unsigned short)r;
}

__device__ inline unsigned short bfc(float f) {  // native cvt (RNE)
  return __builtin_bit_cast(unsigned short, (__bf16)f);
}

__device__ __forceinline__ void gload16(const unsigned short* g,
                                        unsigned short* l) {
  __builtin_amdgcn_global_load_lds(
      (const __attribute__((address_space(1))) void*)g,
      (__attribute__((address_space(3))) void*)l, 16, 0, 0);
}

// ---------------- fp32 -> bf16 convert (no transpose) ----------------
__global__ void cvt_f32_bf16(const float* __restrict__ in,
                             unsigned short* __restrict__ out, int n) {
  int i = (blockIdx.x * blockDim.x + threadIdx.x) * 4;
  if (i + 3 < n) {
    float4 v = *(const float4*)(in + i);
    out[i + 0] = f2bf(v.x);
    out[i + 1] = f2bf(v.y);
    out[i + 2] = f2bf(v.z);
    out[i + 3] = f2bf(v.w);
  } else {
    for (; i < n; ++i) out[i] = f2bf(in[i]);
  }
}

// ---------------- fp32 [K][N] -> bf16 [N][K] transpose ----------------
__global__ __launch_bounds__(256) void cvt_transpose(
    const float* __restrict__ in, unsigned short* __restrict__ out,
    int K, int N) {
  __shared__ unsigned short tile[32][33];
  const int n0 = blockIdx.x * 32;
  const int k0 = blockIdx.y * 32;
  const int tx = threadIdx.x & 31;
  const int ty = threadIdx.x >> 5;  // 0..7
#pragma unroll
  for (int r = ty; r < 32; r += 8)
    tile[r][tx] = f2bf(in[(size_t)(k0 + r) * N + n0 + tx]);
  __syncthreads();
#pragma unroll
  for (int r = ty; r < 32; r += 8)
    out[(size_t)(n0 + r) * K + k0 + tx] = tile[tx][r];
}

// ---------------- bf16 V transpose: [bh][t][64] -> [bh][64][t] ----------
__global__ __launch_bounds__(256) void transpose_v(
    const unsigned short* __restrict__ Vb, unsigned short* __restrict__ Vt) {
  __shared__ unsigned short tile[32][33];
  const int t0 = blockIdx.x * 32;
  const int d0 = blockIdx.y * 32;
  const int bh = blockIdx.z;
  const unsigned short* src = Vb + (size_t)bh * T_SEQ * HEAD_DIM;
  unsigned short* dst = Vt + (size_t)bh * HEAD_DIM * T_SEQ;
  const int tx = threadIdx.x & 31;
  const int ty = threadIdx.x >> 5;
#pragma unroll
  for (int r = ty; r < 32; r += 8)
    tile[r][tx] = src[(size_t)(t0 + r) * HEAD_DIM + d0 + tx];
  __syncthreads();
#pragma unroll
  for (int r = ty; r < 32; r += 8)
    dst[(size_t)(d0 + r) * T_SEQ + t0 + tx] = tile[tx][r];
}

// ---------------- bf16 MFMA GEMM, 128x128 tile, BK=32, global_load_lds --
#define QSCALE 0.1803368801111204f  // 0.125 * log2(e)
template <int EPI>
__global__ __launch_bounds__(256) void gemm_bf16(
    const unsigned short* __restrict__ A,
    const unsigned short* __restrict__ Bt, int M, int N, int K,
    unsigned short* __restrict__ Qb, unsigned short* __restrict__ Kb,
    unsigned short* __restrict__ Vb, float* __restrict__ Cout) {
  const int bn = blockIdx.x * 128;
  const int bm = blockIdx.y * 128;
  const int tid = threadIdx.x;
  const int lane = tid & 63;
  const int w = tid >> 6;
  const int wr = w >> 1, wc = w & 1;  // 2x2 waves, each 64x64
  const int l15 = lane & 15;
  const int lg = lane >> 4;

  __shared__ unsigned short As[128 * 32];
  __shared__ unsigned short Bs[128 * 32];

  floatx4 acc[4][4] = {};

  const int srow = w * 16 + (lane >> 2);  // staging row (0..63)
  const int scol = (lane & 3) * 8;

  for (int k0 = 0; k0 < K; k0 += 32) {
    gload16(&A[(size_t)(bm + srow) * K + k0 + scol], &As[w * 512]);
    gload16(&A[(size_t)(bm + 64 + srow) * K + k0 + scol], &As[2048 + w * 512]);
    gload16(&Bt[(size_t)(bn + srow) * K + k0 + scol], &Bs[w * 512]);
    gload16(&Bt[(size_t)(bn + 64 + srow) * K + k0 + scol], &Bs[2048 + w * 512]);

    __syncthreads();

    bf16x8 af[4], bfr[4];
#pragma unroll
    for (int mt = 0; mt < 4; ++mt)
      af[mt] = *(const bf16x8*)&As[(wr * 64 + mt * 16 + l15) * 32 + lg * 8];
#pragma unroll
    for (int nt = 0; nt < 4; ++nt)
      bfr[nt] = *(const bf16x8*)&Bs[(wc * 64 + nt * 16 + l15) * 32 + lg * 8];
#pragma unroll
    for (int mt = 0; mt < 4; ++mt)
#pragma unroll
      for (int nt = 0; nt < 4; ++nt)
        acc[mt][nt] = __builtin_amdgcn_mfma_f32_16x16x32_bf16(
            af[mt], bfr[nt], acc[mt][nt], 0, 0, 0);

    __syncthreads();
  }

#pragma unroll
  for (int mt = 0; mt < 4; ++mt)
#pragma unroll
    for (int nt = 0; nt < 4; ++nt)
#pragma unroll
      for (int i = 0; i < 4; ++i) {
        int m = bm + wr * 64 + mt * 16 + lg * 4 + i;
        int n = bn + wc * 64 + nt * 16 + l15;
        float v = acc[mt][nt][i];
        if (EPI == 0) {
          int b = m >> 11;
          int t = m & (T_SEQ - 1);
          int part = n >> 10;  // 0=q 1=k 2=v
          int nn = n & (D_MODEL - 1);
          int h = nn >> 6;
          int dh = nn & 63;
          size_t idx = ((size_t)(b * N_HEADS + h) * T_SEQ + t) * HEAD_DIM + dh;
          if (part == 0)
            Qb[idx] = bfc(v * QSCALE);
          else if (part == 1)
            Kb[idx] = bfc(v);
          else
            Vb[idx] = bfc(v);
        } else {
          Cout[(size_t)m * N + n] = v;
        }
      }
}

// ---------------- causal flash attention ----------------
// 4 independent waves/block, 32 q-rows/wave, 64-key steps.
// exp2-domain; lane-partial l (reduced once at end); defer-max THR=8
// with cheap in-lane trigger check (__any ballot), full reduce only on trip.
__global__ __launch_bounds__(256) void attn_fwd(
    const unsigned short* __restrict__ Qb, const unsigned short* __restrict__ Kb,
    const unsigned short* __restrict__ Vt, unsigned short* __restrict__ Ob) {
  const int h64 = blockIdx.x;  // 0..63
  const int wid = threadIdx.x >> 6;
  const int lane = threadIdx.x & 63;
  const int l15 = lane & 15;
  const int lg = lane >> 4;
  const int qi = (15 - blockIdx.y) * 4 + wid;  // heavy tiles dispatched first
  const int q0 = qi * 32;
  const int b = h64 >> 4;
  const int h = h64 & 15;

  const unsigned short* Qh = Qb + (size_t)h64 * T_SEQ * HEAD_DIM;
  const unsigned short* Kh = Kb + (size_t)h64 * T_SEQ * HEAD_DIM;
  const unsigned short* Vh = Vt + (size_t)h64 * HEAD_DIM * T_SEQ;

  __shared__ unsigned short Plds[4][2][16][72];

  bf16x8 qf[2][2];
#pragma unroll
  for (int t = 0; t < 2; ++t)
#pragma unroll
    for (int c = 0; c < 2; ++c)
      qf[t][c] =
          *(const bf16x8*)&Qh[(size_t)(q0 + t * 16 + l15) * 64 + c * 32 + lg * 8];

  floatx4 o[2][4] = {};
  float m_run[2][4], l_part[2][4];
#pragma unroll
  for (int t = 0; t < 2; ++t)
#pragma unroll
    for (int i = 0; i < 4; ++i) {
      m_run[t][i] = -1e30f;
      l_part[t][i] = 0.f;
    }

  const int nst = qi / 2 + 1;
  for (int kb = 0; kb < nst; ++kb) {
    const int kbase = kb * 64;
    const bool last = (kb == nst - 1);

    bf16x8 kf0[4], kf1[4];
#pragma unroll
    for (int c = 0; c < 4; ++c) {
      kf0[c] = *(const bf16x8*)&Kh[(size_t)(kbase + c * 16 + l15) * 64 + lg * 8];
      kf1[c] =
          *(const bf16x8*)&Kh[(size_t)(kbase + c * 16 + l15) * 64 + 32 + lg * 8];
    }
    bf16x8 vf[2][4];
#pragma unroll
    for (int kc = 0; kc < 2; ++kc)
#pragma unroll
      for (int d = 0; d < 4; ++d)
        vf[kc][d] = *(const bf16x8*)&Vh[(size_t)(d * 16 + l15) * T_SEQ + kbase +
                                        kc * 32 + lg * 8];

    floatx4 s[2][4] = {};
    __builtin_amdgcn_s_setprio(1);
#pragma unroll
    for (int c = 0; c < 4; ++c) {
      s[0][c] = __builtin_amdgcn_mfma_f32_16x16x32_bf16(qf[0][0], kf0[c], s[0][c], 0, 0, 0);
      s[0][c] = __builtin_amdgcn_mfma_f32_16x16x32_bf16(qf[0][1], kf1[c], s[0][c], 0, 0, 0);
      s[1][c] = __builtin_amdgcn_mfma_f32_16x16x32_bf16(qf[1][0], kf0[c], s[1][c], 0, 0, 0);
      s[1][c] = __builtin_amdgcn_mfma_f32_16x16x32_bf16(qf[1][1], kf1[c], s[1][c], 0, 0, 0);
    }
    __builtin_amdgcn_s_setprio(0);

    const int kq = kbase - q0;
#pragma unroll
    for (int t = 0; t < 2; ++t) {
      if (last) {
#pragma unroll
        for (int i = 0; i < 4; ++i) {
          int qoff = t * 16 + lg * 4 + i;
#pragma unroll
          for (int c = 0; c < 4; ++c)
            if (c * 16 + l15 + kq > qoff) s[t][c][i] = -1e30f;
        }
      }

      // cheap in-lane max + ballot trigger (no cross-lane reduce usually)
      float lmax[4];
      bool need = false;
#pragma unroll
      for (int i = 0; i < 4; ++i) {
        lmax[i] = fmaxf(fmaxf(s[t][0][i], s[t][1][i]),
                        fmaxf(s[t][2][i], s[t][3][i]));
        need |= (lmax[i] > m_run[t][i] + 8.0f);
      }
      if (__any(need)) {
#pragma unroll
        for (int i = 0; i < 4; ++i) {
          float pm = lmax[i];
          pm = fmaxf(pm, __shfl_xor(pm, 1));
          pm = fmaxf(pm, __shfl_xor(pm, 2));
          pm = fmaxf(pm, __shfl_xor(pm, 4));
          pm = fmaxf(pm, __shfl_xor(pm, 8));
          float mnew = fmaxf(m_run[t][i], pm);
          float alpha = exp2f(m_run[t][i] - mnew);
          m_run[t][i] = mnew;
          l_part[t][i] *= alpha;
          o[t][0][i] *= alpha;
          o[t][1][i] *= alpha;
          o[t][2][i] *= alpha;
          o[t][3][i] *= alpha;
        }
      }
#pragma unroll
      for (int i = 0; i < 4; ++i) {
#pragma unroll
        for (int c = 0; c < 4; ++c) s[t][c][i] = exp2f(s[t][c][i] - m_run[t][i]);
        l_part[t][i] += (s[t][0][i] + s[t][1][i]) + (s[t][2][i] + s[t][3][i]);
#pragma unroll
        for (int c = 0; c < 4; ++c)
          Plds[wid][t][lg * 4 + i][c * 16 + l15] = bfc(s[t][c][i]);
      }
    }

    __builtin_amdgcn_s_setprio(1);
#pragma unroll
    for (int t = 0; t < 2; ++t) {
      bf16x8 pf0 = *(const bf16x8*)&Plds[wid][t][l15][lg * 8];
      bf16x8 pf1 = *(const bf16x8*)&Plds[wid][t][l15][32 + lg * 8];
#pragma unroll
      for (int d = 0; d < 4; ++d) {
        o[t][d] = __builtin_amdgcn_mfma_f32_16x16x32_bf16(pf0, vf[0][d], o[t][d], 0, 0, 0);
        o[t][d] = __builtin_amdgcn_mfma_f32_16x16x32_bf16(pf1, vf[1][d], o[t][d], 0, 0, 0);
      }
    }
    __builtin_amdgcn_s_setprio(0);
  }

#pragma unroll
  for (int t = 0; t < 2; ++t)
#pragma unroll
    for (int i = 0; i < 4; ++i) {
      float l = l_part[t][i];
      l += __shfl_xor(l, 1);
      l += __shfl_xor(l, 2);
      l += __shfl_xor(l, 4);
      l += __shfl_xor(l, 8);
      float inv = 1.0f / l;
      int q = q0 + t * 16 + lg * 4 + i;
      size_t base = ((size_t)(b * T_SEQ + q)) * D_MODEL + h * HEAD_DIM;
#pragma unroll
      for (int d = 0; d < 4; ++d) Ob[base + d * 16 + l15] = bfc(o[t][d][i] * inv);
    }
}

extern "C" void kernel_launch(void* const* d_in, const int* in_sizes, int n_in,
                              void* d_out, int out_size, void* d_ws,
                              size_t ws_size, hipStream_t stream) {
  const float* x = (const float*)d_in[0];
  const float* w_qkv = (const float*)d_in[1];
  const float* w_proj = (const float*)d_in[2];
  float* out = (float*)d_out;

  char* ws = (char*)d_ws;
  size_t off = 0;
  unsigned short* x_bf = (unsigned short*)(ws + off);
  off += (size_t)M_ROWS * D_MODEL * 2;
  unsigned short* wqkv_t = (unsigned short*)(ws + off);
  off += (size_t)D_MODEL * 3 * D_MODEL * 2;
  unsigned short* wproj_t = (unsigned short*)(ws + off);
  off += (size_t)D_MODEL * D_MODEL * 2;
  unsigned short* Qb = (unsigned short*)(ws + off);
  off += (size_t)BH_TOT * T_SEQ * HEAD_DIM * 2;
  unsigned short* Kb = (unsigned short*)(ws + off);
  off += (size_t)BH_TOT * T_SEQ * HEAD_DIM * 2;
  unsigned short* Vb = (unsigned short*)(ws + off);
  off += (size_t)BH_TOT * T_SEQ * HEAD_DIM * 2;
  unsigned short* Vt = (unsigned short*)(ws + off);
  off += (size_t)BH_TOT * T_SEQ * HEAD_DIM * 2;
  unsigned short* Ob = (unsigned short*)(ws + off);
  off += (size_t)M_ROWS * D_MODEL * 2;

  int n1 = M_ROWS * D_MODEL;
  cvt_f32_bf16<<<(n1 / 4 + 255) / 256, 256, 0, stream>>>(x, x_bf, n1);
  cvt_transpose<<<dim3(3 * D_MODEL / 32, D_MODEL / 32), 256, 0, stream>>>(
      w_qkv, wqkv_t, D_MODEL, 3 * D_MODEL);
  cvt_transpose<<<dim3(D_MODEL / 32, D_MODEL / 32), 256, 0, stream>>>(
      w_proj, wproj_t, D_MODEL, D_MODEL);

  gemm_bf16<0><<<dim3(3 * D_MODEL / 128, M_ROWS / 128), 256, 0, stream>>>(
      x_bf, wqkv_t, M_ROWS, 3 * D_MODEL, D_MODEL, Qb, Kb, Vb, nullptr);

  transpose_v<<<dim3(T_SEQ / 32, HEAD_DIM / 32, BH_TOT), 256, 0, stream>>>(Vb, Vt);

  attn_fwd<<<dim3(BH_TOT, T_SEQ / 128), 256, 0, stream>>>(Qb, Kb, Vt, Ob);

  gemm_bf16<1><<<dim3(D_MODEL / 128, M_ROWS / 128), 256, 0, stream>>>(
      Ob, wproj_t, M_ROWS, D_MODEL, D_MODEL, nullptr, nullptr, nullptr, out);
}

// Round 5
// 229.524 us; speedup vs baseline: 1.1791x; 1.1791x over previous
//
#include <hip/hip_runtime.h>
#include <hip/hip_bf16.h>
#include <stdint.h>

#define D_MODEL 1024
#define N_HEADS 16
#define HEAD_DIM 64
#define B_SZ 4
#define T_SEQ 2048
#define BH_TOT (B_SZ * N_HEADS)     // 64
#define M_ROWS (B_SZ * T_SEQ)       // 8192

typedef float floatx4 __attribute__((ext_vector_type(4)));
typedef __bf16 bf16x8 __attribute__((ext_vector_type(8)));

__device__ inline unsigned short f2bf(float f) {
  union { float f; unsigned int u; } c; c.f = f;
  unsigned int u = c.u;
  unsigned int r = (u + 0x7FFFu + ((u >> 16) & 1u)) >> 16;
  return (unsigned short)r;
}

__device__ inline unsigned short bfc(float f) {  // native cvt (RNE)
  return __builtin_bit_cast(unsigned short, (__bf16)f);
}

__device__ __forceinline__ void gload16(const unsigned short* g,
                                        unsigned short* l) {
  __builtin_amdgcn_global_load_lds(
      (const __attribute__((address_space(1))) void*)g,
      (__attribute__((address_space(3))) void*)l, 16, 0, 0);
}

// ---------------- fp32 -> bf16 convert (no transpose) ----------------
__global__ void cvt_f32_bf16(const float* __restrict__ in,
                             unsigned short* __restrict__ out, int n) {
  int i = (blockIdx.x * blockDim.x + threadIdx.x) * 4;
  if (i + 3 < n) {
    float4 v = *(const float4*)(in + i);
    out[i + 0] = f2bf(v.x);
    out[i + 1] = f2bf(v.y);
    out[i + 2] = f2bf(v.z);
    out[i + 3] = f2bf(v.w);
  } else {
    for (; i < n; ++i) out[i] = f2bf(in[i]);
  }
}

// ---------------- fp32 [K][N] -> bf16 [N][K] transpose ----------------
__global__ __launch_bounds__(256) void cvt_transpose(
    const float* __restrict__ in, unsigned short* __restrict__ out,
    int K, int N) {
  __shared__ unsigned short tile[32][33];
  const int n0 = blockIdx.x * 32;
  const int k0 = blockIdx.y * 32;
  const int tx = threadIdx.x & 31;
  const int ty = threadIdx.x >> 5;  // 0..7
#pragma unroll
  for (int r = ty; r < 32; r += 8)
    tile[r][tx] = f2bf(in[(size_t)(k0 + r) * N + n0 + tx]);
  __syncthreads();
#pragma unroll
  for (int r = ty; r < 32; r += 8)
    out[(size_t)(n0 + r) * K + k0 + tx] = tile[tx][r];
}

// ---------------- bf16 V transpose: [bh][t][64] -> [bh][64][t] ----------
__global__ __launch_bounds__(256) void transpose_v(
    const unsigned short* __restrict__ Vb, unsigned short* __restrict__ Vt) {
  __shared__ unsigned short tile[32][33];
  const int t0 = blockIdx.x * 32;
  const int d0 = blockIdx.y * 32;
  const int bh = blockIdx.z;
  const unsigned short* src = Vb + (size_t)bh * T_SEQ * HEAD_DIM;
  unsigned short* dst = Vt + (size_t)bh * HEAD_DIM * T_SEQ;
  const int tx = threadIdx.x & 31;
  const int ty = threadIdx.x >> 5;
#pragma unroll
  for (int r = ty; r < 32; r += 8)
    tile[r][tx] = src[(size_t)(t0 + r) * HEAD_DIM + d0 + tx];
  __syncthreads();
#pragma unroll
  for (int r = ty; r < 32; r += 8)
    dst[(size_t)(d0 + r) * T_SEQ + t0 + tx] = tile[tx][r];
}

// ---------------- bf16 MFMA GEMM, 128x128 tile, BK=32, global_load_lds --
#define QSCALE 0.1803368801111204f  // 0.125 * log2(e)
template <int EPI>
__global__ __launch_bounds__(256) void gemm_bf16(
    const unsigned short* __restrict__ A,
    const unsigned short* __restrict__ Bt, int M, int N, int K,
    unsigned short* __restrict__ Qb, unsigned short* __restrict__ Kb,
    unsigned short* __restrict__ Vb, float* __restrict__ Cout) {
  const int bn = blockIdx.x * 128;
  const int bm = blockIdx.y * 128;
  const int tid = threadIdx.x;
  const int lane = tid & 63;
  const int w = tid >> 6;
  const int wr = w >> 1, wc = w & 1;  // 2x2 waves, each 64x64
  const int l15 = lane & 15;
  const int lg = lane >> 4;

  __shared__ unsigned short As[128 * 32];
  __shared__ unsigned short Bs[128 * 32];

  floatx4 acc[4][4] = {};

  const int srow = w * 16 + (lane >> 2);  // staging row (0..63)
  const int scol = (lane & 3) * 8;

  for (int k0 = 0; k0 < K; k0 += 32) {
    gload16(&A[(size_t)(bm + srow) * K + k0 + scol], &As[w * 512]);
    gload16(&A[(size_t)(bm + 64 + srow) * K + k0 + scol], &As[2048 + w * 512]);
    gload16(&Bt[(size_t)(bn + srow) * K + k0 + scol], &Bs[w * 512]);
    gload16(&Bt[(size_t)(bn + 64 + srow) * K + k0 + scol], &Bs[2048 + w * 512]);

    __syncthreads();

    bf16x8 af[4], bfr[4];
#pragma unroll
    for (int mt = 0; mt < 4; ++mt)
      af[mt] = *(const bf16x8*)&As[(wr * 64 + mt * 16 + l15) * 32 + lg * 8];
#pragma unroll
    for (int nt = 0; nt < 4; ++nt)
      bfr[nt] = *(const bf16x8*)&Bs[(wc * 64 + nt * 16 + l15) * 32 + lg * 8];
#pragma unroll
    for (int mt = 0; mt < 4; ++mt)
#pragma unroll
      for (int nt = 0; nt < 4; ++nt)
        acc[mt][nt] = __builtin_amdgcn_mfma_f32_16x16x32_bf16(
            af[mt], bfr[nt], acc[mt][nt], 0, 0, 0);

    __syncthreads();
  }

#pragma unroll
  for (int mt = 0; mt < 4; ++mt)
#pragma unroll
    for (int nt = 0; nt < 4; ++nt)
#pragma unroll
      for (int i = 0; i < 4; ++i) {
        int m = bm + wr * 64 + mt * 16 + lg * 4 + i;
        int n = bn + wc * 64 + nt * 16 + l15;
        float v = acc[mt][nt][i];
        if (EPI == 0) {
          int b = m >> 11;
          int t = m & (T_SEQ - 1);
          int part = n >> 10;  // 0=q 1=k 2=v
          int nn = n & (D_MODEL - 1);
          int h = nn >> 6;
          int dh = nn & 63;
          size_t idx = ((size_t)(b * N_HEADS + h) * T_SEQ + t) * HEAD_DIM + dh;
          if (part == 0)
            Qb[idx] = bfc(v * QSCALE);
          else if (part == 1)
            Kb[idx] = bfc(v);
          else
            Vb[idx] = bfc(v);
        } else {
          Cout[(size_t)m * N + n] = v;
        }
      }
}

// ---------------- causal flash attention, balanced-pair blocks ----------
// Block (head, p): phase 0 = q-rows [128p,128p+128), phase 1 =
// [2048-128(p+1), 2048-128p). Total 34 KV steps per block, uniform.
// 4 waves x 32 q-rows; K/V chunks (64 keys) reg-prefetched then staged to
// padded LDS shared by all waves. exp2-domain, lane-partial l, defer-max.
__global__ __launch_bounds__(256) void attn_fwd(
    const unsigned short* __restrict__ Qb, const unsigned short* __restrict__ Kb,
    const unsigned short* __restrict__ Vt, unsigned short* __restrict__ Ob) {
  const int head = blockIdx.x;  // 0..63
  const int p = blockIdx.y;     // 0..7
  const int tid = threadIdx.x;
  const int wid = tid >> 6;
  const int lane = tid & 63;
  const int l15 = lane & 15;
  const int lg = lane >> 4;
  const int b = head >> 4;
  const int h = head & 15;

  const unsigned short* Qh = Qb + (size_t)head * T_SEQ * HEAD_DIM;
  const unsigned short* Kh = Kb + (size_t)head * T_SEQ * HEAD_DIM;
  const unsigned short* Vh = Vt + (size_t)head * HEAD_DIM * T_SEQ;

  __shared__ unsigned short Ks[64 * 72];
  __shared__ unsigned short Vs[64 * 72];
  __shared__ unsigned short Plds[4][2][16][72];

  // staging map: thread -> (row, 32B col pair)
  const int st_row = tid >> 2;          // 0..63
  const int st_col = (tid & 3) * 16;    // u16 units: 0,16,32,48

  for (int ph = 0; ph < 2; ++ph) {
    const int rbase = (ph == 0) ? p * 128 : 2048 - 128 * (p + 1);
    const int nst = (ph == 0) ? 2 * p + 2 : 32 - 2 * p;
    const int q0 = rbase + wid * 32;

    bf16x8 qf[2][2];
#pragma unroll
    for (int t = 0; t < 2; ++t)
#pragma unroll
      for (int c = 0; c < 2; ++c)
        qf[t][c] = *(const bf16x8*)&Qh[(size_t)(q0 + t * 16 + l15) * 64 +
                                       c * 32 + lg * 8];

    floatx4 o[2][4] = {};
    float m_run[2][4], l_part[2][4];
#pragma unroll
    for (int t = 0; t < 2; ++t)
#pragma unroll
      for (int i = 0; i < 4; ++i) {
        m_run[t][i] = -1e30f;
        l_part[t][i] = 0.f;
      }

    // prologue: prefetch chunk 0 into regs
    uint4 ka, kb2, va, vb2;
    {
      const uint4* gk = (const uint4*)&Kh[(size_t)st_row * 64 + st_col];
      ka = gk[0]; kb2 = gk[1];
      const uint4* gv = (const uint4*)&Vh[(size_t)st_row * T_SEQ + st_col];
      va = gv[0]; vb2 = gv[1];
    }

    for (int kb = 0; kb < nst; ++kb) {
      const int kbase = kb * 64;
      // write staged regs -> LDS (compiler inserts vmcnt wait)
      *(uint4*)&Ks[st_row * 72 + st_col] = ka;
      *(uint4*)&Ks[st_row * 72 + st_col + 8] = kb2;
      *(uint4*)&Vs[st_row * 72 + st_col] = va;
      *(uint4*)&Vs[st_row * 72 + st_col + 8] = vb2;
      // issue prefetch for next chunk (overlaps with compute below)
      if (kb + 1 < nst) {
        const int nb = kbase + 64;
        const uint4* gk = (const uint4*)&Kh[(size_t)(nb + st_row) * 64 + st_col];
        ka = gk[0]; kb2 = gk[1];
        const uint4* gv = (const uint4*)&Vh[(size_t)st_row * T_SEQ + nb + st_col];
        va = gv[0]; vb2 = gv[1];
      }
      __syncthreads();

      if (kbase <= q0 + 31) {  // this wave still has causal work
        bf16x8 kf0[4], kf1[4];
#pragma unroll
        for (int c = 0; c < 4; ++c) {
          kf0[c] = *(const bf16x8*)&Ks[(c * 16 + l15) * 72 + lg * 8];
          kf1[c] = *(const bf16x8*)&Ks[(c * 16 + l15) * 72 + 32 + lg * 8];
        }
        bf16x8 vf[2][4];
#pragma unroll
        for (int kc = 0; kc < 2; ++kc)
#pragma unroll
          for (int d = 0; d < 4; ++d)
            vf[kc][d] =
                *(const bf16x8*)&Vs[(d * 16 + l15) * 72 + kc * 32 + lg * 8];

        floatx4 s[2][4] = {};
        __builtin_amdgcn_s_setprio(1);
#pragma unroll
        for (int c = 0; c < 4; ++c) {
          s[0][c] = __builtin_amdgcn_mfma_f32_16x16x32_bf16(qf[0][0], kf0[c], s[0][c], 0, 0, 0);
          s[0][c] = __builtin_amdgcn_mfma_f32_16x16x32_bf16(qf[0][1], kf1[c], s[0][c], 0, 0, 0);
          s[1][c] = __builtin_amdgcn_mfma_f32_16x16x32_bf16(qf[1][0], kf0[c], s[1][c], 0, 0, 0);
          s[1][c] = __builtin_amdgcn_mfma_f32_16x16x32_bf16(qf[1][1], kf1[c], s[1][c], 0, 0, 0);
        }
        __builtin_amdgcn_s_setprio(0);

        const int kq = kbase - q0;
        const bool needmask = (kbase + 63 > q0);
#pragma unroll
        for (int t = 0; t < 2; ++t) {
          if (needmask) {
#pragma unroll
            for (int i = 0; i < 4; ++i) {
              int qoff = t * 16 + lg * 4 + i;
#pragma unroll
              for (int c = 0; c < 4; ++c)
                if (c * 16 + l15 + kq > qoff) s[t][c][i] = -1e30f;
            }
          }

          float lmax[4];
          bool need = false;
#pragma unroll
          for (int i = 0; i < 4; ++i) {
            lmax[i] = fmaxf(fmaxf(s[t][0][i], s[t][1][i]),
                            fmaxf(s[t][2][i], s[t][3][i]));
            need |= (lmax[i] > m_run[t][i] + 8.0f);
          }
          if (__any(need)) {
#pragma unroll
            for (int i = 0; i < 4; ++i) {
              float pm = lmax[i];
              pm = fmaxf(pm, __shfl_xor(pm, 1));
              pm = fmaxf(pm, __shfl_xor(pm, 2));
              pm = fmaxf(pm, __shfl_xor(pm, 4));
              pm = fmaxf(pm, __shfl_xor(pm, 8));
              float mnew = fmaxf(m_run[t][i], pm);
              float alpha = exp2f(m_run[t][i] - mnew);
              m_run[t][i] = mnew;
              l_part[t][i] *= alpha;
              o[t][0][i] *= alpha;
              o[t][1][i] *= alpha;
              o[t][2][i] *= alpha;
              o[t][3][i] *= alpha;
            }
          }
#pragma unroll
          for (int i = 0; i < 4; ++i) {
#pragma unroll
            for (int c = 0; c < 4; ++c)
              s[t][c][i] = exp2f(s[t][c][i] - m_run[t][i]);
            l_part[t][i] += (s[t][0][i] + s[t][1][i]) + (s[t][2][i] + s[t][3][i]);
#pragma unroll
            for (int c = 0; c < 4; ++c)
              Plds[wid][t][lg * 4 + i][c * 16 + l15] = bfc(s[t][c][i]);
          }
        }

        __builtin_amdgcn_s_setprio(1);
#pragma unroll
        for (int t = 0; t < 2; ++t) {
          bf16x8 pf0 = *(const bf16x8*)&Plds[wid][t][l15][lg * 8];
          bf16x8 pf1 = *(const bf16x8*)&Plds[wid][t][l15][32 + lg * 8];
#pragma unroll
          for (int d = 0; d < 4; ++d) {
            o[t][d] = __builtin_amdgcn_mfma_f32_16x16x32_bf16(pf0, vf[0][d], o[t][d], 0, 0, 0);
            o[t][d] = __builtin_amdgcn_mfma_f32_16x16x32_bf16(pf1, vf[1][d], o[t][d], 0, 0, 0);
          }
        }
        __builtin_amdgcn_s_setprio(0);
      }

      __syncthreads();
    }

#pragma unroll
    for (int t = 0; t < 2; ++t)
#pragma unroll
      for (int i = 0; i < 4; ++i) {
        float l = l_part[t][i];
        l += __shfl_xor(l, 1);
        l += __shfl_xor(l, 2);
        l += __shfl_xor(l, 4);
        l += __shfl_xor(l, 8);
        float inv = 1.0f / l;
        int q = q0 + t * 16 + lg * 4 + i;
        size_t base = ((size_t)(b * T_SEQ + q)) * D_MODEL + h * HEAD_DIM;
#pragma unroll
        for (int d = 0; d < 4; ++d)
          Ob[base + d * 16 + l15] = bfc(o[t][d][i] * inv);
      }
  }
}

extern "C" void kernel_launch(void* const* d_in, const int* in_sizes, int n_in,
                              void* d_out, int out_size, void* d_ws,
                              size_t ws_size, hipStream_t stream) {
  const float* x = (const float*)d_in[0];
  const float* w_qkv = (const float*)d_in[1];
  const float* w_proj = (const float*)d_in[2];
  float* out = (float*)d_out;

  char* ws = (char*)d_ws;
  size_t off = 0;
  unsigned short* x_bf = (unsigned short*)(ws + off);
  off += (size_t)M_ROWS * D_MODEL * 2;
  unsigned short* wqkv_t = (unsigned short*)(ws + off);
  off += (size_t)D_MODEL * 3 * D_MODEL * 2;
  unsigned short* wproj_t = (unsigned short*)(ws + off);
  off += (size_t)D_MODEL * D_MODEL * 2;
  unsigned short* Qb = (unsigned short*)(ws + off);
  off += (size_t)BH_TOT * T_SEQ * HEAD_DIM * 2;
  unsigned short* Kb = (unsigned short*)(ws + off);
  off += (size_t)BH_TOT * T_SEQ * HEAD_DIM * 2;
  unsigned short* Vb = (unsigned short*)(ws + off);
  off += (size_t)BH_TOT * T_SEQ * HEAD_DIM * 2;
  unsigned short* Vt = (unsigned short*)(ws + off);
  off += (size_t)BH_TOT * T_SEQ * HEAD_DIM * 2;
  unsigned short* Ob = (unsigned short*)(ws + off);
  off += (size_t)M_ROWS * D_MODEL * 2;

  int n1 = M_ROWS * D_MODEL;
  cvt_f32_bf16<<<(n1 / 4 + 255) / 256, 256, 0, stream>>>(x, x_bf, n1);
  cvt_transpose<<<dim3(3 * D_MODEL / 32, D_MODEL / 32), 256, 0, stream>>>(
      w_qkv, wqkv_t, D_MODEL, 3 * D_MODEL);
  cvt_transpose<<<dim3(D_MODEL / 32, D_MODEL / 32), 256, 0, stream>>>(
      w_proj, wproj_t, D_MODEL, D_MODEL);

  gemm_bf16<0><<<dim3(3 * D_MODEL / 128, M_ROWS / 128), 256, 0, stream>>>(
      x_bf, wqkv_t, M_ROWS, 3 * D_MODEL, D_MODEL, Qb, Kb, Vb, nullptr);

  transpose_v<<<dim3(T_SEQ / 32, HEAD_DIM / 32, BH_TOT), 256, 0, stream>>>(Vb, Vt);

  attn_fwd<<<dim3(BH_TOT, 8), 256, 0, stream>>>(Qb, Kb, Vt, Ob);

  gemm_bf16<1><<<dim3(D_MODEL / 128, M_ROWS / 128), 256, 0, stream>>>(
      Ob, wproj_t, M_ROWS, D_MODEL, D_MODEL, nullptr, nullptr, nullptr, out);
}